// Round 1
// baseline (14597.220 us; speedup 1.0000x reference)
//
#include <hip/hip_runtime.h>
#include <hip/hip_bf16.h>

typedef __bf16 bf16;
typedef __attribute__((ext_vector_type(8))) __bf16 bf16x8;
typedef __attribute__((ext_vector_type(4))) float f32x4;

#define BM 128
#define BN 128
#define BK 32
#define LDK 40   // padded LDS row stride (bf16 elems): 80B rows, 16B-aligned, 2-way bank alias (free)

// C[M][N] = A[M][K] * W[N][K]^T + bias[N]; A,W,bias,C all fp32; compute in bf16 MFMA.
__global__ __launch_bounds__(256) void gemm_bt(
    const float* __restrict__ A, const float* __restrict__ W,
    const float* __restrict__ bias, float* __restrict__ C,
    int M, int N, int K)
{
    __shared__ bf16 As[BM][LDK];
    __shared__ bf16 Bs[BN][LDK];

    const int tid  = threadIdx.x;
    const int brow = blockIdx.y * BM;
    const int bcol = blockIdx.x * BN;

    const int wave = tid >> 6;
    const int lane = tid & 63;
    const int wr = wave >> 1, wc = wave & 1;   // wave -> 64x64 quadrant
    const int lo = lane & 15, hi = lane >> 4;

    f32x4 acc[4][4];
#pragma unroll
    for (int m = 0; m < 4; ++m)
#pragma unroll
        for (int n = 0; n < 4; ++n)
            acc[m][n] = (f32x4){0.f, 0.f, 0.f, 0.f};

    // staging: thread t covers row = t>>1 (0..127), k-halfblock = (t&1)*16
    const int srow = tid >> 1;
    const int skb  = (tid & 1) * 16;

    for (int k0 = 0; k0 < K; k0 += BK) {
        const float* pa = A + (size_t)(brow + srow) * K + k0 + skb;
        const float* pb = W + (size_t)(bcol + srow) * K + k0 + skb;
        float fa[16], fb[16];
#pragma unroll
        for (int i = 0; i < 4; ++i) {
            f32x4 va = *(const f32x4*)(pa + i * 4);
            f32x4 vb = *(const f32x4*)(pb + i * 4);
#pragma unroll
            for (int j = 0; j < 4; ++j) { fa[i * 4 + j] = va[j]; fb[i * 4 + j] = vb[j]; }
        }
        bf16x8 ha0, ha1, hb0, hb1;
#pragma unroll
        for (int j = 0; j < 8; ++j) {
            ha0[j] = (bf16)fa[j]; ha1[j] = (bf16)fa[8 + j];
            hb0[j] = (bf16)fb[j]; hb1[j] = (bf16)fb[8 + j];
        }
        *(bf16x8*)&As[srow][skb]     = ha0;
        *(bf16x8*)&As[srow][skb + 8] = ha1;
        *(bf16x8*)&Bs[srow][skb]     = hb0;
        *(bf16x8*)&Bs[srow][skb + 8] = hb1;

        __syncthreads();

        bf16x8 af[4], bfr[4];
#pragma unroll
        for (int m = 0; m < 4; ++m)
            af[m] = *(const bf16x8*)&As[wr * 64 + m * 16 + lo][hi * 8];
#pragma unroll
        for (int n = 0; n < 4; ++n)
            bfr[n] = *(const bf16x8*)&Bs[wc * 64 + n * 16 + lo][hi * 8];

#pragma unroll
        for (int m = 0; m < 4; ++m)
#pragma unroll
            for (int n = 0; n < 4; ++n)
                acc[m][n] = __builtin_amdgcn_mfma_f32_16x16x32_bf16(af[m], bfr[n], acc[m][n], 0, 0, 0);

        __syncthreads();
    }

    // epilogue: C/D layout row=(lane>>4)*4+r, col=lane&15
#pragma unroll
    for (int m = 0; m < 4; ++m) {
        const int row = brow + wr * 64 + m * 16 + hi * 4;
#pragma unroll
        for (int n = 0; n < 4; ++n) {
            const int col = bcol + wc * 64 + n * 16 + lo;
            const float bv = bias[col];
#pragma unroll
            for (int r = 0; r < 4; ++r)
                C[(size_t)(row + r) * N + col] = acc[m][n][r] + bv;
        }
    }
}

// Flash-style causal+ALiBi attention, fp32 VALU.
// grid: (S/64 q-blocks, H heads), 256 threads. 4 threads per q-row (d split in 4x32).
__global__ __launch_bounds__(256) void attn_kernel(
    const float* __restrict__ qkv, float* __restrict__ attn_out)
{
    const int S = 2048, QKV = 12288, D = 4096, HD = 128;
    const int h    = blockIdx.y;
    const int q0   = blockIdx.x * 64;
    const int tid  = threadIdx.x;
    const int wave = tid >> 6, lane = tid & 63;
    const int lrow = lane >> 2, part = lane & 3;
    const int qrow = q0 + wave * 16 + lrow;
    const int dbase = part * 32;

    const float scale = 0.08838834764831845f;         // 1/sqrt(128)
    const float slope = exp2f(-0.25f * (float)(h + 1)); // alibi slope, H=32 (power of 2)

    const float* Qp = qkv + (size_t)qrow * QKV + h * HD + dbase;
    float qreg[32];
#pragma unroll
    for (int i = 0; i < 8; ++i) {
        f32x4 v = *(const f32x4*)(Qp + i * 4);
#pragma unroll
        for (int j = 0; j < 4; ++j) qreg[i * 4 + j] = v[j];
    }

    float acc[32];
#pragma unroll
    for (int j = 0; j < 32; ++j) acc[j] = 0.f;
    float mrun = -1e30f, lsum = 0.f;

    const int kvmax = q0 + wave * 16 + 15;  // max q-row in this wave
    const float* Kbase = qkv + (size_t)D + h * HD + dbase;       // K at col offset 4096
    const float* Vbase = qkv + (size_t)2 * D + h * HD + dbase;   // V at col offset 8192

    for (int kv = 0; kv <= kvmax; ++kv) {
        const float* kp = Kbase + (size_t)kv * QKV;
        float dot = 0.f;
#pragma unroll
        for (int i = 0; i < 8; ++i) {
            f32x4 v = *(const f32x4*)(kp + i * 4);
#pragma unroll
            for (int j = 0; j < 4; ++j) dot += qreg[i * 4 + j] * v[j];
        }
        dot += __shfl_xor(dot, 1);
        dot += __shfl_xor(dot, 2);

        float score = dot * scale + slope * (float)(kv - (S - 1));
        if (kv > qrow) score = -1e30f;  // causal mask

        float p;
        if (score <= mrun) {
            p = __expf(score - mrun);
            lsum += p;
        } else {
            const float c = __expf(mrun - score);
            lsum = lsum * c + 1.f;
            mrun = score;
#pragma unroll
            for (int j = 0; j < 32; ++j) acc[j] *= c;
            p = 1.f;
        }

        const float* vp = Vbase + (size_t)kv * QKV;
#pragma unroll
        for (int i = 0; i < 8; ++i) {
            f32x4 v = *(const f32x4*)(vp + i * 4);
#pragma unroll
            for (int j = 0; j < 4; ++j) acc[i * 4 + j] += p * v[j];
        }
    }

    const float inv = 1.f / lsum;
    float* op = attn_out + (size_t)qrow * D + h * HD + dbase;
#pragma unroll
    for (int i = 0; i < 8; ++i) {
        f32x4 v;
#pragma unroll
        for (int j = 0; j < 4; ++j) v[j] = acc[i * 4 + j] * inv;
        *(f32x4*)(op + i * 4) = v;
    }
}

extern "C" void kernel_launch(void* const* d_in, const int* in_sizes, int n_in,
                              void* d_out, int out_size, void* d_ws, size_t ws_size,
                              hipStream_t stream) {
    const int S = 2048, D = 4096, QKV = 12288, H = 32;
    const float* x     = (const float*)d_in[0];
    const float* w_qkv = (const float*)d_in[1];
    const float* b_qkv = (const float*)d_in[2];
    const float* w_out = (const float*)d_in[3];
    const float* b_out = (const float*)d_in[4];
    float* out = (float*)d_out;

    float* qkv  = (float*)d_ws;                       // [2048][12288] fp32 = 100.7 MB
    float* attn = qkv + (size_t)S * QKV;              // [2048][4096]  fp32 =  33.6 MB

    // 1) QKV projection: [S,D] x [3D,D]^T -> [S,3D]
    gemm_bt<<<dim3(QKV / BN, S / BM), 256, 0, stream>>>(x, w_qkv, b_qkv, qkv, S, QKV, D);
    // 2) causal ALiBi attention
    attn_kernel<<<dim3(S / 64, H), 256, 0, stream>>>(qkv, attn);
    // 3) output projection: [S,D] x [D,D]^T -> [S,D]
    gemm_bt<<<dim3(D / BN, S / BM), 256, 0, stream>>>(attn, w_out, b_out, out, S, D, D);
}

// Round 2
// 961.787 us; speedup vs baseline: 15.1772x; 15.1772x over previous
//
#include <hip/hip_runtime.h>
#include <hip/hip_bf16.h>

typedef __bf16 bf16;
typedef __attribute__((ext_vector_type(8))) __bf16 bf16x8;
typedef __attribute__((ext_vector_type(4))) float f32x4;

#define BM 128
#define BN 128
#define BK 32
#define LDK 40   // padded LDS row stride (bf16 elems): 80B rows, 16B-aligned, 2-way bank alias (free)

// C[M][N] = A[M][K] * W[N][K]^T + bias[N]; A,W,bias,C all fp32; compute in bf16 MFMA.
__global__ __launch_bounds__(256) void gemm_bt(
    const float* __restrict__ A, const float* __restrict__ W,
    const float* __restrict__ bias, float* __restrict__ C,
    int M, int N, int K)
{
    __shared__ bf16 As[BM][LDK];
    __shared__ bf16 Bs[BN][LDK];

    const int tid  = threadIdx.x;
    const int brow = blockIdx.y * BM;
    const int bcol = blockIdx.x * BN;

    const int wave = tid >> 6;
    const int lane = tid & 63;
    const int wr = wave >> 1, wc = wave & 1;   // wave -> 64x64 quadrant
    const int lo = lane & 15, hi = lane >> 4;

    f32x4 acc[4][4];
#pragma unroll
    for (int m = 0; m < 4; ++m)
#pragma unroll
        for (int n = 0; n < 4; ++n)
            acc[m][n] = (f32x4){0.f, 0.f, 0.f, 0.f};

    // staging: thread t covers row = t>>1 (0..127), k-halfblock = (t&1)*16
    const int srow = tid >> 1;
    const int skb  = (tid & 1) * 16;

    for (int k0 = 0; k0 < K; k0 += BK) {
        const float* pa = A + (size_t)(brow + srow) * K + k0 + skb;
        const float* pb = W + (size_t)(bcol + srow) * K + k0 + skb;
        float fa[16], fb[16];
#pragma unroll
        for (int i = 0; i < 4; ++i) {
            f32x4 va = *(const f32x4*)(pa + i * 4);
            f32x4 vb = *(const f32x4*)(pb + i * 4);
#pragma unroll
            for (int j = 0; j < 4; ++j) { fa[i * 4 + j] = va[j]; fb[i * 4 + j] = vb[j]; }
        }
        bf16x8 ha0, ha1, hb0, hb1;
#pragma unroll
        for (int j = 0; j < 8; ++j) {
            ha0[j] = (bf16)fa[j]; ha1[j] = (bf16)fa[8 + j];
            hb0[j] = (bf16)fb[j]; hb1[j] = (bf16)fb[8 + j];
        }
        *(bf16x8*)&As[srow][skb]     = ha0;
        *(bf16x8*)&As[srow][skb + 8] = ha1;
        *(bf16x8*)&Bs[srow][skb]     = hb0;
        *(bf16x8*)&Bs[srow][skb + 8] = hb1;

        __syncthreads();

        bf16x8 af[4], bfr[4];
#pragma unroll
        for (int m = 0; m < 4; ++m)
            af[m] = *(const bf16x8*)&As[wr * 64 + m * 16 + lo][hi * 8];
#pragma unroll
        for (int n = 0; n < 4; ++n)
            bfr[n] = *(const bf16x8*)&Bs[wc * 64 + n * 16 + lo][hi * 8];

#pragma unroll
        for (int m = 0; m < 4; ++m)
#pragma unroll
            for (int n = 0; n < 4; ++n)
                acc[m][n] = __builtin_amdgcn_mfma_f32_16x16x32_bf16(af[m], bfr[n], acc[m][n], 0, 0, 0);

        __syncthreads();
    }

    // epilogue: C/D layout row=(lane>>4)*4+r, col=lane&15
#pragma unroll
    for (int m = 0; m < 4; ++m) {
        const int row = brow + wr * 64 + m * 16 + hi * 4;
#pragma unroll
        for (int n = 0; n < 4; ++n) {
            const int col = bcol + wc * 64 + n * 16 + lo;
            const float bv = bias[col];
#pragma unroll
            for (int r = 0; r < 4; ++r)
                C[(size_t)(row + r) * N + col] = acc[m][n][r] + bv;
        }
    }
}

// MFMA flash attention, causal + ALiBi.
// grid: (S/64, H). 256 threads = 4 waves; wave w owns q-rows [q0+16w, q0+16w+16).
// Per KV tile of 32: stage K (XOR-swizzled [32][128]) + V^T ([128][40]) in LDS as bf16,
// QK^T via 8 mfma, online softmax in C-layout, P through per-wave LDS, PV via 8 mfma.
__global__ __launch_bounds__(256) void attn_mfma(
    const float* __restrict__ qkv, float* __restrict__ attn_out)
{
    const int S = 2048, QKV = 12288, D = 4096, HD = 128;
    const int h   = blockIdx.y;
    const int q0  = blockIdx.x * 64;
    const int tid = threadIdx.x;
    const int w    = tid >> 6, lane = tid & 63;
    const int lo   = lane & 15, hi = lane >> 4;
    const int qbase = q0 + w * 16;

    __shared__ bf16 Ks[32 * 128];      // [kv][d], elem idx ^ ((kv&7)<<3)
    __shared__ bf16 Vs[128 * 40];      // [d][kv], rows padded to 40 (80B, 16B-aligned)
    __shared__ bf16 Ps[4 * 16 * 40];   // per-wave [q][kv] P tile, rows padded to 40

    const float scale = 0.08838834764831845f;            // 1/sqrt(128)
    const float slope = exp2f(-0.25f * (float)(h + 1));  // H=32 (pow2) alibi slope

    // Q A-fragments (reused all tiles): lane -> q = qbase+lo, k = ds*32 + hi*8 + i
    bf16x8 qfrag[4];
#pragma unroll
    for (int ds = 0; ds < 4; ++ds) {
        const float* qp = qkv + (size_t)(qbase + lo) * QKV + h * HD + ds * 32 + hi * 8;
        f32x4 a = *(const f32x4*)qp;
        f32x4 b = *(const f32x4*)(qp + 4);
        bf16x8 f;
#pragma unroll
        for (int j = 0; j < 4; ++j) { f[j] = (bf16)a[j]; f[4 + j] = (bf16)b[j]; }
        qfrag[ds] = f;
    }

    f32x4 o[8];
#pragma unroll
    for (int dt = 0; dt < 8; ++dt) o[dt] = (f32x4){0.f, 0.f, 0.f, 0.f};
    float mrow[4] = {-1e30f, -1e30f, -1e30f, -1e30f};
    float lrow[4] = {0.f, 0.f, 0.f, 0.f};

    const int srow   = tid >> 3;   // staging kv-row 0..31
    const int schunk = tid & 7;    // 16-float chunk of the 128-wide row

    const int ntile = (q0 + 64) / 32;
    for (int t = 0; t < ntile; ++t) {
        const int kv0 = t * 32;
        // ---- stage K (swizzled natural) + V (transposed) ----
        {
            const float* kp = qkv + (size_t)(kv0 + srow) * QKV + D + h * HD + schunk * 16;
            float f[16];
#pragma unroll
            for (int i = 0; i < 4; ++i) {
                f32x4 v = *(const f32x4*)(kp + i * 4);
#pragma unroll
                for (int j = 0; j < 4; ++j) f[i * 4 + j] = v[j];
            }
            bf16x8 h0, h1;
#pragma unroll
            for (int j = 0; j < 8; ++j) { h0[j] = (bf16)f[j]; h1[j] = (bf16)f[8 + j]; }
            const int base = srow * 128 + schunk * 16;
            const int swz  = (srow & 7) << 3;
            *(bf16x8*)&Ks[(base) ^ swz]     = h0;
            *(bf16x8*)&Ks[(base + 8) ^ swz] = h1;

            const float* vp = qkv + (size_t)(kv0 + srow) * QKV + 2 * D + h * HD + schunk * 16;
#pragma unroll
            for (int i = 0; i < 4; ++i) {
                f32x4 v = *(const f32x4*)(vp + i * 4);
#pragma unroll
                for (int j = 0; j < 4; ++j)
                    Vs[(schunk * 16 + i * 4 + j) * 40 + srow] = (bf16)v[j];
            }
        }
        __syncthreads();

        if (kv0 <= qbase + 15) {   // skip fully-masked tiles (barriers stay uniform)
            // ---- QK^T: C[q][kv], two 16-col subtiles ----
            f32x4 c0 = (f32x4){0.f,0.f,0.f,0.f}, c1 = (f32x4){0.f,0.f,0.f,0.f};
#pragma unroll
            for (int ds = 0; ds < 4; ++ds) {
                const int r0 = lo, r1 = 16 + lo;
                bf16x8 b0 = *(const bf16x8*)&Ks[(r0 * 128 + ds * 32 + hi * 8) ^ ((r0 & 7) << 3)];
                bf16x8 b1 = *(const bf16x8*)&Ks[(r1 * 128 + ds * 32 + hi * 8) ^ ((r1 & 7) << 3)];
                c0 = __builtin_amdgcn_mfma_f32_16x16x32_bf16(qfrag[ds], b0, c0, 0, 0, 0);
                c1 = __builtin_amdgcn_mfma_f32_16x16x32_bf16(qfrag[ds], b1, c1, 0, 0, 0);
            }
            // ---- online softmax; C layout: row q = qbase+hi*4+r, col kv = kv0+lo (+16) ----
#pragma unroll
            for (int r = 0; r < 4; ++r) {
                const int q   = qbase + hi * 4 + r;
                const int k0i = kv0 + lo, k1i = kv0 + 16 + lo;
                float s0 = c0[r] * scale + slope * (float)(k0i - (S - 1));
                float s1 = c1[r] * scale + slope * (float)(k1i - (S - 1));
                if (k0i > q) s0 = -1e30f;
                if (k1i > q) s1 = -1e30f;
                float tm = fmaxf(s0, s1);
                tm = fmaxf(tm, __shfl_xor(tm, 1));
                tm = fmaxf(tm, __shfl_xor(tm, 2));
                tm = fmaxf(tm, __shfl_xor(tm, 4));
                tm = fmaxf(tm, __shfl_xor(tm, 8));
                const float mnew = fmaxf(mrow[r], tm);
                const float cr = __expf(mrow[r] - mnew);   // 0 on first tile (mrow=-1e30)
                const float p0 = __expf(s0 - mnew);        // 0 where masked
                const float p1 = __expf(s1 - mnew);
                float ps = p0 + p1;
                ps += __shfl_xor(ps, 1);
                ps += __shfl_xor(ps, 2);
                ps += __shfl_xor(ps, 4);
                ps += __shfl_xor(ps, 8);
                lrow[r] = lrow[r] * cr + ps;
                mrow[r] = mnew;
#pragma unroll
                for (int dt = 0; dt < 8; ++dt) o[dt][r] *= cr;
                Ps[w * 640 + (hi * 4 + r) * 40 + lo]      = (bf16)p0;
                Ps[w * 640 + (hi * 4 + r) * 40 + lo + 16] = (bf16)p1;
            }
            // ---- PV: A = P[q][kv] (per-wave LDS round-trip), B = V^T[d][kv] ----
            bf16x8 pa = *(const bf16x8*)&Ps[w * 640 + lo * 40 + hi * 8];
#pragma unroll
            for (int dt = 0; dt < 8; ++dt) {
                bf16x8 bv = *(const bf16x8*)&Vs[(dt * 16 + lo) * 40 + hi * 8];
                o[dt] = __builtin_amdgcn_mfma_f32_16x16x32_bf16(pa, bv, o[dt], 0, 0, 0);
            }
        }
        __syncthreads();
    }

    // ---- epilogue: normalize and store (C layout rows) ----
#pragma unroll
    for (int r = 0; r < 4; ++r) {
        const float inv = 1.0f / lrow[r];
        const int q = qbase + hi * 4 + r;
        float* op = attn_out + (size_t)q * D + h * HD;
#pragma unroll
        for (int dt = 0; dt < 8; ++dt)
            op[dt * 16 + lo] = o[dt][r] * inv;
    }
}

extern "C" void kernel_launch(void* const* d_in, const int* in_sizes, int n_in,
                              void* d_out, int out_size, void* d_ws, size_t ws_size,
                              hipStream_t stream) {
    const int S = 2048, D = 4096, QKV = 12288, H = 32;
    const float* x     = (const float*)d_in[0];
    const float* w_qkv = (const float*)d_in[1];
    const float* b_qkv = (const float*)d_in[2];
    const float* w_out = (const float*)d_in[3];
    const float* b_out = (const float*)d_in[4];
    float* out = (float*)d_out;

    float* qkv  = (float*)d_ws;                       // [2048][12288] fp32 = 100.7 MB
    float* attn = qkv + (size_t)S * QKV;              // [2048][4096]  fp32 =  33.6 MB

    // 1) QKV projection: [S,D] x [3D,D]^T -> [S,3D]
    gemm_bt<<<dim3(QKV / BN, S / BM), 256, 0, stream>>>(x, w_qkv, b_qkv, qkv, S, QKV, D);
    // 2) causal ALiBi attention (MFMA flash)
    attn_mfma<<<dim3(S / 64, H), 256, 0, stream>>>(qkv, attn);
    // 3) output projection: [S,D] x [D,D]^T -> [S,D]
    gemm_bt<<<dim3(D / BN, S / BM), 256, 0, stream>>>(attn, w_out, b_out, out, S, D, D);
}

// Round 3
// 767.910 us; speedup vs baseline: 19.0090x; 1.2525x over previous
//
#include <hip/hip_runtime.h>
#include <hip/hip_bf16.h>

typedef __bf16 bf16;
typedef __attribute__((ext_vector_type(8))) __bf16 bf16x8;
typedef __attribute__((ext_vector_type(4))) float f32x4;

#define GLOAD_LDS16(g, l)                                                        \
    __builtin_amdgcn_global_load_lds(                                            \
        (const __attribute__((address_space(1))) void*)(g),                      \
        (__attribute__((address_space(3))) void*)(l), 16, 0, 0)

// ---------------- fp32 -> bf16 conversion (vectorized, grid-stride) ----------------
__global__ __launch_bounds__(256) void cvt_f32_bf16(
    const float* __restrict__ src, bf16* __restrict__ dst, int n16)
{
    int idx = blockIdx.x * 256 + threadIdx.x;
    const int stride = gridDim.x * 256;
    for (int i = idx; i < n16; i += stride) {
        const float* p = src + (size_t)i * 16;
        f32x4 a = *(const f32x4*)p;
        f32x4 b = *(const f32x4*)(p + 4);
        f32x4 c = *(const f32x4*)(p + 8);
        f32x4 d = *(const f32x4*)(p + 12);
        bf16x8 h0, h1;
#pragma unroll
        for (int j = 0; j < 4; ++j) {
            h0[j] = (bf16)a[j]; h0[4 + j] = (bf16)b[j];
            h1[j] = (bf16)c[j]; h1[4 + j] = (bf16)d[j];
        }
        bf16* q = dst + (size_t)i * 16;
        *(bf16x8*)q = h0;
        *(bf16x8*)(q + 8) = h1;
    }
}

// ---------------- m97-structure GEMM: C = A[M][K] * B[N][K]^T + bias ----------------
// bf16 A,B (global), fp32 accumulate; OUT_BF16 selects output type. Linear LDS +
// global_load_lds width-16 staging, 128x128 tile, BK=32, 4 waves.
template <int OUT_BF16>
__global__ __launch_bounds__(256) void gemm_glds(
    const bf16* __restrict__ A, const bf16* __restrict__ B,
    const float* __restrict__ bias, void* __restrict__ Cout,
    int K, int ldc)
{
    __shared__ bf16 As[128 * 32];
    __shared__ bf16 Bs[128 * 32];

    const int tid  = threadIdx.x;
    const int wv   = tid >> 6, lane = tid & 63;
    const int lo   = lane & 15, hi = lane >> 4;
    const int wr   = wv >> 1, wc = wv & 1;
    const int brow = blockIdx.y * 128;
    const int bcol = blockIdx.x * 128;

    f32x4 acc[4][4];
#pragma unroll
    for (int m = 0; m < 4; ++m)
#pragma unroll
        for (int n = 0; n < 4; ++n)
            acc[m][n] = (f32x4){0.f, 0.f, 0.f, 0.f};

    // staging: chunk c = wv*2+i covers LDS bytes [c*1024, c*1024+1024) = rows c*16..c*16+15
    // lane l -> row c*16 + (l>>2), col (l&3)*8 (16B); LDS dest is wave-uniform base + lane*16
    const int srow = lane >> 2;          // 0..15
    const int scol = (lane & 3) * 8;     // bf16 col offset

    for (int k0 = 0; k0 < K; k0 += 32) {
#pragma unroll
        for (int i = 0; i < 2; ++i) {
            const int c = wv * 2 + i;
            const int row = c * 16 + srow;
            GLOAD_LDS16(A + (size_t)(brow + row) * K + k0 + scol, &As[c * 512]);
            GLOAD_LDS16(B + (size_t)(bcol + row) * K + k0 + scol, &Bs[c * 512]);
        }
        __syncthreads();

        bf16x8 af[4], bf[4];
#pragma unroll
        for (int m = 0; m < 4; ++m)
            af[m] = *(const bf16x8*)&As[(wr * 64 + m * 16 + lo) * 32 + hi * 8];
#pragma unroll
        for (int n = 0; n < 4; ++n)
            bf[n] = *(const bf16x8*)&Bs[(wc * 64 + n * 16 + lo) * 32 + hi * 8];

#pragma unroll
        for (int m = 0; m < 4; ++m)
#pragma unroll
            for (int n = 0; n < 4; ++n)
                acc[m][n] = __builtin_amdgcn_mfma_f32_16x16x32_bf16(af[m], bf[n], acc[m][n], 0, 0, 0);

        __syncthreads();
    }

    // epilogue: C/D layout row=(lane>>4)*4+r, col=lane&15
#pragma unroll
    for (int m = 0; m < 4; ++m) {
        const int row = brow + wr * 64 + m * 16 + hi * 4;
#pragma unroll
        for (int n = 0; n < 4; ++n) {
            const int col = bcol + wc * 64 + n * 16 + lo;
            const float bv = bias[col];
#pragma unroll
            for (int r = 0; r < 4; ++r) {
                const float v = acc[m][n][r] + bv;
                if (OUT_BF16)
                    ((bf16*)Cout)[(size_t)(row + r) * ldc + col] = (bf16)v;
                else
                    ((float*)Cout)[(size_t)(row + r) * ldc + col] = v;
            }
        }
    }
}

// ---------------- MFMA flash attention, causal + ALiBi, bf16 in/out ----------------
// grid: (S/64, H). 4 waves; wave w owns q-rows [q0+16w, q0+16w+16). KV tile = 32.
__global__ __launch_bounds__(256) void attn_mfma(
    const bf16* __restrict__ qkv, bf16* __restrict__ attn_out)
{
    const int S = 2048, QKV = 12288, D = 4096, HD = 128;
    const int h   = blockIdx.y;
    const int q0  = blockIdx.x * 64;
    const int tid = threadIdx.x;
    const int w    = tid >> 6, lane = tid & 63;
    const int lo   = lane & 15, hi = lane >> 4;
    const int qbase = q0 + w * 16;

    __shared__ bf16 Ks[32 * 128];      // [kv][d], elem idx ^ ((kv&7)<<3)
    __shared__ bf16 Vs[128 * 40];      // [d][kv], rows padded to 40
    __shared__ bf16 Ps[4 * 16 * 40];   // per-wave [q][kv] P tile

    const float scale = 0.08838834764831845f;            // 1/sqrt(128)
    const float slope = exp2f(-0.25f * (float)(h + 1));  // H=32 alibi slope

    bf16x8 qfrag[4];
#pragma unroll
    for (int ds = 0; ds < 4; ++ds)
        qfrag[ds] = *(const bf16x8*)(qkv + (size_t)(qbase + lo) * QKV + h * HD + ds * 32 + hi * 8);

    f32x4 o[8];
#pragma unroll
    for (int dt = 0; dt < 8; ++dt) o[dt] = (f32x4){0.f, 0.f, 0.f, 0.f};
    float mrow[4] = {-1e30f, -1e30f, -1e30f, -1e30f};
    float lrow[4] = {0.f, 0.f, 0.f, 0.f};

    const int srow   = tid >> 3;   // staging kv-row 0..31
    const int schunk = tid & 7;    // 16-elem chunk of the 128-wide row

    const int ntile = (q0 + 64) / 32;
    for (int t = 0; t < ntile; ++t) {
        const int kv0 = t * 32;
        {
            const bf16* kp = qkv + (size_t)(kv0 + srow) * QKV + D + h * HD + schunk * 16;
            bf16x8 h0 = *(const bf16x8*)kp;
            bf16x8 h1 = *(const bf16x8*)(kp + 8);
            const int base = srow * 128 + schunk * 16;
            const int swz  = (srow & 7) << 3;
            *(bf16x8*)&Ks[base ^ swz]       = h0;
            *(bf16x8*)&Ks[(base + 8) ^ swz] = h1;

            const bf16* vp = qkv + (size_t)(kv0 + srow) * QKV + 2 * D + h * HD + schunk * 16;
#pragma unroll
            for (int i = 0; i < 16; ++i)
                Vs[(schunk * 16 + i) * 40 + srow] = vp[i];
        }
        __syncthreads();

        if (kv0 <= qbase + 15) {
            f32x4 c0 = (f32x4){0.f,0.f,0.f,0.f}, c1 = (f32x4){0.f,0.f,0.f,0.f};
#pragma unroll
            for (int ds = 0; ds < 4; ++ds) {
                const int r0 = lo, r1 = 16 + lo;
                bf16x8 b0 = *(const bf16x8*)&Ks[(r0 * 128 + ds * 32 + hi * 8) ^ ((r0 & 7) << 3)];
                bf16x8 b1 = *(const bf16x8*)&Ks[(r1 * 128 + ds * 32 + hi * 8) ^ ((r1 & 7) << 3)];
                c0 = __builtin_amdgcn_mfma_f32_16x16x32_bf16(qfrag[ds], b0, c0, 0, 0, 0);
                c1 = __builtin_amdgcn_mfma_f32_16x16x32_bf16(qfrag[ds], b1, c1, 0, 0, 0);
            }
#pragma unroll
            for (int r = 0; r < 4; ++r) {
                const int q   = qbase + hi * 4 + r;
                const int k0i = kv0 + lo, k1i = kv0 + 16 + lo;
                float s0 = c0[r] * scale + slope * (float)(k0i - (S - 1));
                float s1 = c1[r] * scale + slope * (float)(k1i - (S - 1));
                if (k0i > q) s0 = -1e30f;
                if (k1i > q) s1 = -1e30f;
                float tm = fmaxf(s0, s1);
                tm = fmaxf(tm, __shfl_xor(tm, 1));
                tm = fmaxf(tm, __shfl_xor(tm, 2));
                tm = fmaxf(tm, __shfl_xor(tm, 4));
                tm = fmaxf(tm, __shfl_xor(tm, 8));
                const float mnew = fmaxf(mrow[r], tm);
                const float cr = __expf(mrow[r] - mnew);
                const float p0 = __expf(s0 - mnew);
                const float p1 = __expf(s1 - mnew);
                float ps = p0 + p1;
                ps += __shfl_xor(ps, 1);
                ps += __shfl_xor(ps, 2);
                ps += __shfl_xor(ps, 4);
                ps += __shfl_xor(ps, 8);
                lrow[r] = lrow[r] * cr + ps;
                mrow[r] = mnew;
#pragma unroll
                for (int dt = 0; dt < 8; ++dt) o[dt][r] *= cr;
                Ps[w * 640 + (hi * 4 + r) * 40 + lo]      = (bf16)p0;
                Ps[w * 640 + (hi * 4 + r) * 40 + lo + 16] = (bf16)p1;
            }
            bf16x8 pa = *(const bf16x8*)&Ps[w * 640 + lo * 40 + hi * 8];
#pragma unroll
            for (int dt = 0; dt < 8; ++dt) {
                bf16x8 bv = *(const bf16x8*)&Vs[(dt * 16 + lo) * 40 + hi * 8];
                o[dt] = __builtin_amdgcn_mfma_f32_16x16x32_bf16(pa, bv, o[dt], 0, 0, 0);
            }
        }
        __syncthreads();
    }

#pragma unroll
    for (int r = 0; r < 4; ++r) {
        const float inv = 1.0f / lrow[r];
        const int q = qbase + hi * 4 + r;
        bf16* op = attn_out + (size_t)q * D + h * HD;
#pragma unroll
        for (int dt = 0; dt < 8; ++dt)
            op[dt * 16 + lo] = (bf16)(o[dt][r] * inv);
    }
}

extern "C" void kernel_launch(void* const* d_in, const int* in_sizes, int n_in,
                              void* d_out, int out_size, void* d_ws, size_t ws_size,
                              hipStream_t stream) {
    const int S = 2048, D = 4096, QKV = 12288;
    const int NH = 6144;  // QKV GEMM N-half
    const float* x     = (const float*)d_in[0];
    const float* w_qkv = (const float*)d_in[1];
    const float* b_qkv = (const float*)d_in[2];
    const float* w_out = (const float*)d_in[3];
    const float* b_out = (const float*)d_in[4];
    float* out = (float*)d_out;

    // ws layout (bytes): [0, 16.8M) xb, later attnb; [16.8M, 67.1M) wb, later wob;
    // [67.1M, 117.4M) qkvb. Peak 112 MiB.
    char* ws = (char*)d_ws;
    bf16* xb    = (bf16*)ws;                                   // [2048][4096]
    bf16* attnb = (bf16*)ws;                                   // [2048][4096] (after xb dead)
    bf16* wb    = (bf16*)(ws + (size_t)S * D * 2);             // [6144][4096] weight half
    bf16* wob   = wb;                                          // [4096][4096] (after wb dead)
    bf16* qkvb  = (bf16*)(ws + (size_t)S * D * 2 + (size_t)NH * D * 2);  // [2048][12288]

    // 1) convert x
    cvt_f32_bf16<<<2048, 256, 0, stream>>>(x, xb, S * D / 16);
    // 2) QKV projection in two N-halves sharing wb
    cvt_f32_bf16<<<2048, 256, 0, stream>>>(w_qkv, wb, NH * D / 16);
    gemm_glds<1><<<dim3(NH / 128, S / 128), 256, 0, stream>>>(xb, wb, b_qkv, qkvb, D, QKV);
    cvt_f32_bf16<<<2048, 256, 0, stream>>>(w_qkv + (size_t)NH * D, wb, NH * D / 16);
    gemm_glds<1><<<dim3(NH / 128, S / 128), 256, 0, stream>>>(xb, wb, b_qkv + NH, qkvb + NH, D, QKV);
    // 3) attention (reads qkvb, writes attnb over dead xb)
    attn_mfma<<<dim3(S / 64, 32), 256, 0, stream>>>(qkvb, attnb);
    // 4) out projection
    cvt_f32_bf16<<<2048, 256, 0, stream>>>(w_out, wob, D * D / 16);
    gemm_glds<0><<<dim3(D / 128, S / 128), 256, 0, stream>>>(attnb, wob, b_out, out, D, D);
}

// Round 4
// 573.688 us; speedup vs baseline: 25.4445x; 1.3386x over previous
//
#include <hip/hip_runtime.h>
#include <hip/hip_bf16.h>

typedef __bf16 bf16;
typedef __attribute__((ext_vector_type(8))) __bf16 bf16x8;
typedef __attribute__((ext_vector_type(4))) float f32x4;

#define GLOAD_LDS16(g, l)                                                        \
    __builtin_amdgcn_global_load_lds(                                            \
        (const __attribute__((address_space(1))) void*)(g),                      \
        (__attribute__((address_space(3))) void*)(l), 16, 0, 0)

// ---------------- fp32 -> bf16 conversion (vectorized, grid-stride) ----------------
__global__ __launch_bounds__(256) void cvt_f32_bf16(
    const float* __restrict__ src, bf16* __restrict__ dst, int n16)
{
    int idx = blockIdx.x * 256 + threadIdx.x;
    const int stride = gridDim.x * 256;
    for (int i = idx; i < n16; i += stride) {
        const float* p = src + (size_t)i * 16;
        f32x4 a = *(const f32x4*)p;
        f32x4 b = *(const f32x4*)(p + 4);
        f32x4 c = *(const f32x4*)(p + 8);
        f32x4 d = *(const f32x4*)(p + 12);
        bf16x8 h0, h1;
#pragma unroll
        for (int j = 0; j < 4; ++j) {
            h0[j] = (bf16)a[j]; h0[4 + j] = (bf16)b[j];
            h1[j] = (bf16)c[j]; h1[4 + j] = (bf16)d[j];
        }
        bf16* q = dst + (size_t)i * 16;
        *(bf16x8*)q = h0;
        *(bf16x8*)(q + 8) = h1;
    }
}

// ---------------- m97-structure GEMM: C = A[M][K] * B[N][K]^T + bias ----------------
template <int OUT_BF16>
__global__ __launch_bounds__(256) void gemm_glds(
    const bf16* __restrict__ A, const bf16* __restrict__ B,
    const float* __restrict__ bias, void* __restrict__ Cout,
    int K, int ldc)
{
    __shared__ bf16 As[128 * 32];
    __shared__ bf16 Bs[128 * 32];

    const int tid  = threadIdx.x;
    const int wv   = tid >> 6, lane = tid & 63;
    const int lo   = lane & 15, hi = lane >> 4;
    const int wr   = wv >> 1, wc = wv & 1;
    const int brow = blockIdx.y * 128;
    const int bcol = blockIdx.x * 128;

    f32x4 acc[4][4];
#pragma unroll
    for (int m = 0; m < 4; ++m)
#pragma unroll
        for (int n = 0; n < 4; ++n)
            acc[m][n] = (f32x4){0.f, 0.f, 0.f, 0.f};

    const int srow = lane >> 2;
    const int scol = (lane & 3) * 8;

    for (int k0 = 0; k0 < K; k0 += 32) {
#pragma unroll
        for (int i = 0; i < 2; ++i) {
            const int c = wv * 2 + i;
            const int row = c * 16 + srow;
            GLOAD_LDS16(A + (size_t)(brow + row) * K + k0 + scol, &As[c * 512]);
            GLOAD_LDS16(B + (size_t)(bcol + row) * K + k0 + scol, &Bs[c * 512]);
        }
        __syncthreads();

        bf16x8 af[4], bf[4];
#pragma unroll
        for (int m = 0; m < 4; ++m)
            af[m] = *(const bf16x8*)&As[(wr * 64 + m * 16 + lo) * 32 + hi * 8];
#pragma unroll
        for (int n = 0; n < 4; ++n)
            bf[n] = *(const bf16x8*)&Bs[(wc * 64 + n * 16 + lo) * 32 + hi * 8];

#pragma unroll
        for (int m = 0; m < 4; ++m)
#pragma unroll
            for (int n = 0; n < 4; ++n)
                acc[m][n] = __builtin_amdgcn_mfma_f32_16x16x32_bf16(af[m], bf[n], acc[m][n], 0, 0, 0);

        __syncthreads();
    }

#pragma unroll
    for (int m = 0; m < 4; ++m) {
        const int row = brow + wr * 64 + m * 16 + hi * 4;
#pragma unroll
        for (int n = 0; n < 4; ++n) {
            const int col = bcol + wc * 64 + n * 16 + lo;
            const float bv = bias[col];
#pragma unroll
            for (int r = 0; r < 4; ++r) {
                const float v = acc[m][n][r] + bv;
                if (OUT_BF16)
                    ((bf16*)Cout)[(size_t)(row + r) * ldc + col] = (bf16)v;
                else
                    ((float*)Cout)[(size_t)(row + r) * ldc + col] = v;
            }
        }
    }
}

// ---------------- MFMA flash attention v2: causal + ALiBi, bf16 in/out ----------------
// 1D grid of 512 blocks, 512 threads (8 waves). head = bid&31 (same head -> same XCD),
// qi descending for load balance. q-tile = 128 rows (16/wave), KVBLK = 64.
// K: [64][128] XOR-swizzled (byte ^ (kv&7)<<4), vector-staged.
// V: transposed [128 d][72] rows (64 kv + pad); staged by (d, 8kv)-owner threads:
//    8 scalar global loads -> 1 ds_write_b128 (2-way banks = free).
__global__ __launch_bounds__(512) void attn_mfma(
    const bf16* __restrict__ qkv, bf16* __restrict__ attn_out)
{
    const int S = 2048, QKV = 12288, D = 4096, HD = 128;
    const int bid = blockIdx.x;
    const int h   = bid & 31;
    const int qi  = 15 - (bid >> 5);
    const int q0  = qi * 128;
    const int tid = threadIdx.x;
    const int w    = tid >> 6, lane = tid & 63;
    const int lo   = lane & 15, hi = lane >> 4;
    const int qbase = q0 + w * 16;

    __shared__ bf16 Ks[64 * 128];       // [kv][d], elem idx ^ ((kv&7)<<3)
    __shared__ bf16 Vs[128 * 72];       // [d][kv], rows padded 64->72
    __shared__ bf16 Ps[8 * 16 * 72];    // per-wave [q][kv] P tile, stride 72

    const float scale = 0.08838834764831845f;            // 1/sqrt(128)
    const float slope = exp2f(-0.25f * (float)(h + 1));  // H=32 alibi slope

    // Q A-fragments: lane -> q = qbase+lo, k = ds*32 + hi*8 + j
    bf16x8 qfrag[4];
#pragma unroll
    for (int ds = 0; ds < 4; ++ds)
        qfrag[ds] = *(const bf16x8*)(qkv + (size_t)(qbase + lo) * QKV + h * HD + ds * 32 + hi * 8);

    f32x4 o[8];
#pragma unroll
    for (int dt = 0; dt < 8; ++dt) o[dt] = (f32x4){0.f, 0.f, 0.f, 0.f};
    float mrow[4] = {-1e30f, -1e30f, -1e30f, -1e30f};
    float lrow[4] = {0.f, 0.f, 0.f, 0.f};

    // staging roles
    const int krow = tid >> 3;        // K: kv row 0..63
    const int kch  = tid & 7;         // K: 16-elem d-chunk
    const int vd   = tid & 127;       // V: d 0..127
    const int vkh  = tid >> 7;        // V: kv 16-group 0..3

    const int ntile = (q0 + 128) / 64;
    for (int t = 0; t < ntile; ++t) {
        const int kv0 = t * 64;
        // ---- K stage (vectorized, swizzled) ----
        {
            const bf16* kp = qkv + (size_t)(kv0 + krow) * QKV + D + h * HD + kch * 16;
            bf16x8 k0 = *(const bf16x8*)kp;
            bf16x8 k1 = *(const bf16x8*)(kp + 8);
            const int kb  = krow * 128 + kch * 16;
            const int swz = (krow & 7) << 3;
            *(bf16x8*)&Ks[kb ^ swz]       = k0;
            *(bf16x8*)&Ks[(kb + 8) ^ swz] = k1;
        }
        // ---- V stage transposed: thread owns (d=vd, kv=vkh*16..+15) ----
        {
            const bf16* vp = qkv + (size_t)(kv0 + vkh * 16) * QKV + 2 * D + h * HD + vd;
            bf16x8 v0, v1;
#pragma unroll
            for (int j = 0; j < 8; ++j) {
                v0[j] = vp[(size_t)j * QKV];
                v1[j] = vp[(size_t)(8 + j) * QKV];
            }
            *(bf16x8*)&Vs[vd * 72 + vkh * 16]     = v0;
            *(bf16x8*)&Vs[vd * 72 + vkh * 16 + 8] = v1;
        }
        __syncthreads();

        if (kv0 <= qbase + 15) {
            // ---- QK^T: C[q][kv], four 16-col subtiles ----
            f32x4 c[4];
#pragma unroll
            for (int j = 0; j < 4; ++j) c[j] = (f32x4){0.f, 0.f, 0.f, 0.f};
            __builtin_amdgcn_s_setprio(1);
#pragma unroll
            for (int ds = 0; ds < 4; ++ds) {
#pragma unroll
                for (int j = 0; j < 4; ++j) {
                    const int r = j * 16 + lo;
                    bf16x8 b = *(const bf16x8*)&Ks[(r * 128 + ds * 32 + hi * 8) ^ ((r & 7) << 3)];
                    c[j] = __builtin_amdgcn_mfma_f32_16x16x32_bf16(qfrag[ds], b, c[j], 0, 0, 0);
                }
            }
            __builtin_amdgcn_s_setprio(0);
            // ---- online softmax; C layout: row q = qbase+hi*4+r, col kv = kv0+j*16+lo ----
#pragma unroll
            for (int r = 0; r < 4; ++r) {
                const int q = qbase + hi * 4 + r;
                float s[4];
#pragma unroll
                for (int j = 0; j < 4; ++j) {
                    const int ki = kv0 + j * 16 + lo;
                    s[j] = c[j][r] * scale + slope * (float)(ki - (S - 1));
                    if (ki > q) s[j] = -1e30f;
                }
                float tm = fmaxf(fmaxf(s[0], s[1]), fmaxf(s[2], s[3]));
                tm = fmaxf(tm, __shfl_xor(tm, 1));
                tm = fmaxf(tm, __shfl_xor(tm, 2));
                tm = fmaxf(tm, __shfl_xor(tm, 4));
                tm = fmaxf(tm, __shfl_xor(tm, 8));
                const float mnew = fmaxf(mrow[r], tm);
                const float cr = __expf(mrow[r] - mnew);
                float p[4], ps = 0.f;
#pragma unroll
                for (int j = 0; j < 4; ++j) { p[j] = __expf(s[j] - mnew); ps += p[j]; }
                ps += __shfl_xor(ps, 1);
                ps += __shfl_xor(ps, 2);
                ps += __shfl_xor(ps, 4);
                ps += __shfl_xor(ps, 8);
                lrow[r] = lrow[r] * cr + ps;
                mrow[r] = mnew;
#pragma unroll
                for (int dt = 0; dt < 8; ++dt) o[dt][r] *= cr;
#pragma unroll
                for (int j = 0; j < 4; ++j)
                    Ps[w * 1152 + (hi * 4 + r) * 72 + j * 16 + lo] = (bf16)p[j];
            }
            // ---- PV: A = P[q][kv] (per-wave LDS), B = V^T[d][kv] ----
            bf16x8 pa0 = *(const bf16x8*)&Ps[w * 1152 + lo * 72 + hi * 8];
            bf16x8 pa1 = *(const bf16x8*)&Ps[w * 1152 + lo * 72 + 32 + hi * 8];
            __builtin_amdgcn_s_setprio(1);
#pragma unroll
            for (int dt = 0; dt < 8; ++dt) {
                bf16x8 bv0 = *(const bf16x8*)&Vs[(dt * 16 + lo) * 72 + hi * 8];
                bf16x8 bv1 = *(const bf16x8*)&Vs[(dt * 16 + lo) * 72 + 32 + hi * 8];
                o[dt] = __builtin_amdgcn_mfma_f32_16x16x32_bf16(pa0, bv0, o[dt], 0, 0, 0);
                o[dt] = __builtin_amdgcn_mfma_f32_16x16x32_bf16(pa1, bv1, o[dt], 0, 0, 0);
            }
            __builtin_amdgcn_s_setprio(0);
        }
        __syncthreads();
    }

#pragma unroll
    for (int r = 0; r < 4; ++r) {
        const float inv = 1.0f / lrow[r];
        const int q = qbase + hi * 4 + r;
        bf16* op = attn_out + (size_t)q * D + h * HD;
#pragma unroll
        for (int dt = 0; dt < 8; ++dt)
            op[dt * 16 + lo] = (bf16)(o[dt][r] * inv);
    }
}

extern "C" void kernel_launch(void* const* d_in, const int* in_sizes, int n_in,
                              void* d_out, int out_size, void* d_ws, size_t ws_size,
                              hipStream_t stream) {
    const int S = 2048, D = 4096, QKV = 12288;
    const int NH = 6144;
    const float* x     = (const float*)d_in[0];
    const float* w_qkv = (const float*)d_in[1];
    const float* b_qkv = (const float*)d_in[2];
    const float* w_out = (const float*)d_in[3];
    const float* b_out = (const float*)d_in[4];
    float* out = (float*)d_out;

    char* ws = (char*)d_ws;
    bf16* xb    = (bf16*)ws;                                   // [2048][4096]
    bf16* attnb = (bf16*)ws;                                   // reuses xb after death
    bf16* wb    = (bf16*)(ws + (size_t)S * D * 2);             // [6144][4096] weight half
    bf16* wob   = wb;                                          // reuses wb after death
    bf16* qkvb  = (bf16*)(ws + (size_t)S * D * 2 + (size_t)NH * D * 2);  // [2048][12288]

    cvt_f32_bf16<<<2048, 256, 0, stream>>>(x, xb, S * D / 16);
    cvt_f32_bf16<<<2048, 256, 0, stream>>>(w_qkv, wb, NH * D / 16);
    gemm_glds<1><<<dim3(NH / 128, S / 128), 256, 0, stream>>>(xb, wb, b_qkv, qkvb, D, QKV);
    cvt_f32_bf16<<<2048, 256, 0, stream>>>(w_qkv + (size_t)NH * D, wb, NH * D / 16);
    gemm_glds<1><<<dim3(NH / 128, S / 128), 256, 0, stream>>>(xb, wb, b_qkv + NH, qkvb + NH, D, QKV);
    attn_mfma<<<512, 512, 0, stream>>>(qkvb, attnb);
    cvt_f32_bf16<<<2048, 256, 0, stream>>>(w_out, wob, D * D / 16);
    gemm_glds<0><<<dim3(D / 128, S / 128), 256, 0, stream>>>(attnb, wob, b_out, out, D, D);
}